// Round 14
// baseline (36.673 us; speedup 1.0000x reference)
//
#include <hip/hip_runtime.h>
#include <math.h>

// SeesawLoss forward: B=8192 rows, C=4096 classes, P=0.8, Q=2.0, EPS=0.01
// Log-space algebra (no M2, no pass-3 transcendentals):
//   L    = logsumexp(o) ;  Koff = L + max(o_t - L, log(EPS))
//   g_j  = exp(o_j - Koff) (= sratio_j); exp(logit_j - Koff) = mit_j*max(g^3,g)
//   mit_j = min(powacc_j/powacc_t, 1)  [powacc = acc^0.8, monotone -> pred ok]
//   nll_b = Koff + log(Z) - o_t,  Z = sum_j mit_j*max(g_j^3, g_j)
// Range-safe: g <= 100 -> Z <= 4e9; Z >= g_t > 0. j==t term = g_t (mask-free).
//
// Shape = R11 (best, 34.3us): 256 thr/block, 1 row/block, 16 floats/thread in
// 4 named float4s, powacc prefetched with the row (R8/R12/R13: more data per
// thread or per block regresses). This round: k_row's SECOND barrier removed —
// waves write pass-3 partials (zpart[b*4+w]) + block scalar (aux[b] = Koff-o_t)
// to global and retire; k_reduce applies log(Z) per row in the same fixed
// order (bitwise-identical result). NO grid-wide atomics (R4/R5: ~670us).

#define CC 4096

__device__ __forceinline__ float wave_max(float v) {
    #pragma unroll
    for (int o = 32; o > 0; o >>= 1) v = fmaxf(v, __shfl_xor(v, o, 64));
    return v;
}
__device__ __forceinline__ float wave_sum(float v) {
    #pragma unroll
    for (int o = 32; o > 0; o >>= 1) v += __shfl_xor(v, o, 64);
    return v;
}

// exp each component against lane max (in place), return component sum
__device__ __forceinline__ float exp4(float4& v, float m) {
    v.x = __expf(v.x - m); v.y = __expf(v.y - m);
    v.z = __expf(v.z - m); v.w = __expf(v.w - m);
    return (v.x + v.y) + (v.z + v.w);
}

// pass-3 term sum for one float4 of e-values (8 VALU ops/element, no trans)
__device__ __forceinline__ float zsum4(float4 e, float4 pa, float rt, float c) {
    float gx = e.x * c, gy = e.y * c, gz = e.z * c, gw = e.w * c;
    float hx = fmaxf(gx * gx * gx, gx), hy = fmaxf(gy * gy * gy, gy);
    float hz = fmaxf(gz * gz * gz, gz), hw = fmaxf(gw * gw * gw, gw);
    float mx = fminf(pa.x * rt, 1.f),  my = fminf(pa.y * rt, 1.f);
    float mz = fminf(pa.z * rt, 1.f),  mw = fminf(pa.w * rt, 1.f);
    return (hx * mx + hy * my) + (hz * mz + hw * mw);
}

// One block: bincount via LDS atomics -> clamp -> powacc = acc^0.8 table.
__global__ __launch_bounds__(1024) void k_hist(const int* __restrict__ tg, int B,
                                               float* __restrict__ powacc) {
    __shared__ int hacc[CC];
    const int tid = threadIdx.x;
    #pragma unroll
    for (int k = 0; k < CC / 1024; ++k) hacc[tid + k * 1024] = 0;
    __syncthreads();
    const int4* __restrict__ tg4 = (const int4*)tg;
    for (int i = tid; i < B / 4; i += 1024) {
        int4 tv = tg4[i];
        atomicAdd(&hacc[tv.x], 1); atomicAdd(&hacc[tv.y], 1);
        atomicAdd(&hacc[tv.z], 1); atomicAdd(&hacc[tv.w], 1);
    }
    __syncthreads();
    #pragma unroll
    for (int k = 0; k < CC / 1024; ++k) {
        int i = tid + k * 1024;
        int a = hacc[i];
        if (a < 1) a = 1;                       // clamp(min=1)
        powacc[i] = __powf((float)a, 0.8f);     // acc^P
    }
}

__global__ __launch_bounds__(256, 8) void k_row(const float* __restrict__ outp,
                                                const int* __restrict__ tg,
                                                const float* __restrict__ powacc,
                                                float* __restrict__ zpart,
                                                float* __restrict__ aux) {
    __shared__ float2 red_ms[4];

    const int b   = blockIdx.x;
    const int tid = threadIdx.x;
    const int w   = tid >> 6;
    const bool lane0 = (tid & 63) == 0;

    const float LOG_EPS = -4.605170185988091f;   // log(0.01)

    // scalar chain early (critical path to Koff / rt)
    const int   t    = tg[b];
    const float o_t  = outp[(size_t)b * CC + t];
    const float pa_t = powacc[t];

    const float4* __restrict__ src = (const float4*)(outp + (size_t)b * CC);
    const float4* __restrict__ pac = (const float4*)powacc;

    // ---- all 8 loads issued together: row + powacc prefetch (rule #20 safe) ----
    float4 v0 = src[tid];
    float4 v1 = src[tid + 256];
    float4 v2 = src[tid + 512];
    float4 v3 = src[tid + 768];
    float4 pa0 = pac[tid];
    float4 pa1 = pac[tid + 256];
    float4 pa2 = pac[tid + 512];
    float4 pa3 = pac[tid + 768];

    // ---- lane-local max ----
    float m0 = fmaxf(fmaxf(v0.x, v0.y), fmaxf(v0.z, v0.w));
    float m1 = fmaxf(fmaxf(v1.x, v1.y), fmaxf(v1.z, v1.w));
    float m2 = fmaxf(fmaxf(v2.x, v2.y), fmaxf(v2.z, v2.w));
    float m3 = fmaxf(fmaxf(v3.x, v3.y), fmaxf(v3.z, v3.w));
    const float mlane = fmaxf(fmaxf(m0, m1), fmaxf(m2, m3));

    // wave max (DS pipe) overlaps the exp pass (trans pipe)
    const float mw = wave_max(mlane);

    // e_j = exp(o_j - m_lane) in place; lane-relative sum
    float s = (exp4(v0, mlane) + exp4(v1, mlane)) +
              (exp4(v2, mlane) + exp4(v3, mlane));

    // rebase once to wave max, then plain sum-reduce
    float S_w = wave_sum(s * __expf(mlane - mw));
    if (lane0) red_ms[w] = make_float2(mw, S_w);
    __syncthreads();                       // the ONLY barrier in k_row

    // cross-wave merge: max tree + 4 parallel exps (uniform on all threads)
    const float M = fmaxf(fmaxf(red_ms[0].x, red_ms[1].x),
                          fmaxf(red_ms[2].x, red_ms[3].x));
    const float S = red_ms[0].y * __expf(red_ms[0].x - M)
                  + red_ms[1].y * __expf(red_ms[1].x - M)
                  + red_ms[2].y * __expf(red_ms[2].x - M)
                  + red_ms[3].y * __expf(red_ms[3].x - M);
    const float L       = M + __logf(S);                 // true logsumexp
    const float logclip = fmaxf(o_t - L, LOG_EPS);       // log(max(p_t, EPS))
    const float Koff    = L + logclip;                   // g_j = exp(o_j - Koff)

    if (tid == 0) aux[b] = Koff - o_t;     // block scalar out, overlaps pass 3

    const float c  = __expf(mlane - Koff);               // g_j = e_j * c
    const float rt = __fdividef(1.0f, pa_t);

    // ---- pass 3: pure-VALU seesaw terms, 4 independent accumulators ----
    float z0 = zsum4(v0, pa0, rt, c);
    float z1 = zsum4(v1, pa1, rt, c);
    float z2 = zsum4(v2, pa2, rt, c);
    float z3 = zsum4(v3, pa3, rt, c);
    float z  = wave_sum((z0 + z1) + (z2 + z3));

    // each wave writes its partial and retires — no second barrier
    if (lane0) zpart[(b << 2) + w] = z;
}

// deterministic final: per-row nll = aux + log(sum of 4 wave partials),
// then fixed strided partials + fixed tree for the mean.
__global__ __launch_bounds__(1024) void k_reduce(const float* __restrict__ zpart,
                                                 const float* __restrict__ aux,
                                                 float* __restrict__ out, int B) {
    __shared__ float red[16];
    const int tid = threadIdx.x;
    const float4* __restrict__ z4 = (const float4*)zpart;
    float s = 0.f;
    for (int i = tid; i < B; i += 1024) {
        float4 zp = z4[i];                       // the 4 wave partials of row i
        float Z = (zp.x + zp.y) + (zp.z + zp.w); // same order as old k_row
        s += aux[i] + __logf(Z);
    }
    s = wave_sum(s);
    if ((tid & 63) == 0) red[tid >> 6] = s;
    __syncthreads();
    if (tid == 0) {
        float tsum = 0.f;
        #pragma unroll
        for (int k = 0; k < 16; ++k) tsum += red[k];
        out[0] = tsum / (float)B;
    }
}

extern "C" void kernel_launch(void* const* d_in, const int* in_sizes, int n_in,
                              void* d_out, int out_size, void* d_ws, size_t ws_size,
                              hipStream_t stream) {
    const float* outp = (const float*)d_in[0];   // [B, C] f32
    const int*   tg   = (const int*)d_in[1];     // [B] i32
    float*       out  = (float*)d_out;           // scalar f32

    const int B = in_sizes[1];                   // 8192 (C fixed at 4096)

    char*  ws     = (char*)d_ws;
    float* powacc = (float*)ws;                  // 16 KB
    float* zpart  = (float*)(ws + 16384);        // B*4*4 = 128 KB
    float* aux    = (float*)(ws + 16384 + 131072); // B*4 = 32 KB

    k_hist  <<<1, 1024, 0, stream>>>(tg, B, powacc);
    k_row   <<<B, 256, 0, stream>>>(outp, tg, powacc, zpart, aux);
    k_reduce<<<1, 1024, 0, stream>>>(zpart, aux, out, B);
}